// Round 5
// baseline (334.750 us; speedup 1.0000x reference)
//
#include <hip/hip_runtime.h>

// Problem constants (B=8, T=4096, C=512)
#define BB 8
#define TT 4096
#define CC 512
#define MM (BB * TT)   // 32768 rows
#define SS 128         // scan chunks
#define LL 32          // steps per chunk (SS*LL == TT)

typedef short short8 __attribute__((ext_vector_type(8)));
typedef unsigned short ushort8 __attribute__((ext_vector_type(8)));
typedef float f32x4 __attribute__((ext_vector_type(4)));

__device__ __forceinline__ unsigned short f2bf(float f) {
    unsigned int u = __float_as_uint(f);
    u += 0x7FFFu + ((u >> 16) & 1u);   // RNE
    return (unsigned short)(u >> 16);
}
__device__ __forceinline__ float bf2f(unsigned short h) {
    return __uint_as_float(((unsigned int)h) << 16);
}

// async global->LDS, 16B per lane. LDS dest must be wave-uniform base + lane*16.
__device__ __forceinline__ void gl_lds16(const void* g, void* l) {
    __builtin_amdgcn_global_load_lds(
        (__attribute__((address_space(1))) void*)(unsigned long long)g,
        (__attribute__((address_space(3))) void*)(unsigned int)(unsigned long long)l,
        16, 0, 0);
}

__device__ __forceinline__ ushort8 pack8(f32x4 a, f32x4 b) {
    ushort8 r;
    r[0] = f2bf(a.x); r[1] = f2bf(a.y); r[2] = f2bf(a.z); r[3] = f2bf(a.w);
    r[4] = f2bf(b.x); r[5] = f2bf(b.y); r[6] = f2bf(b.z); r[7] = f2bf(b.w);
    return r;
}

// ---------------------------------------------------------------------------
// Kernel 1: transpose + bf16-convert the four 512x512 weights. wT[n][k]=w[k][n]
// ---------------------------------------------------------------------------
__global__ void transpose_w(const float* __restrict__ wk, const float* __restrict__ wv,
                            const float* __restrict__ wr, const float* __restrict__ wo,
                            unsigned short* __restrict__ wT) {
    const int which = blockIdx.y;
    const float* src = (which == 0) ? wk : (which == 1) ? wv : (which == 2) ? wr : wo;
    const int i = blockIdx.x * 256 + threadIdx.x;
    const int n = i >> 9;
    const int k = i & 511;
    wT[(size_t)which * (CC * CC) + i] = f2bf(src[(size_t)k * CC + n]);
}

// ---------------------------------------------------------------------------
// Kernel 2: time-shift mix for all three branches in one memory-bound pass.
// ---------------------------------------------------------------------------
__global__ __launch_bounds__(256) void mix_kvr(
    const float* __restrict__ x,
    const float* __restrict__ mixk, const float* __restrict__ mixv,
    const float* __restrict__ mixr,
    unsigned short* __restrict__ kx, unsigned short* __restrict__ vx,
    unsigned short* __restrict__ rx) {
    const int idx = blockIdx.x * 256 + threadIdx.x;   // 0 .. MM*CC/8-1
    const int row = idx >> 6;
    const int ch  = (idx & 63) * 8;
    const int t   = row & (TT - 1);
    const size_t off = (size_t)row * CC + ch;
    const float* xr = x + off;

    const f32x4 zero4 = {0.f, 0.f, 0.f, 0.f};
    const f32x4 one4  = {1.f, 1.f, 1.f, 1.f};

    f32x4 xc0 = ((const f32x4*)xr)[0];
    f32x4 xc1 = ((const f32x4*)xr)[1];
    f32x4 xp0 = zero4, xp1 = zero4;
    if (t != 0) {
        xp0 = ((const f32x4*)(xr - CC))[0];
        xp1 = ((const f32x4*)(xr - CC))[1];
    }

    f32x4 m0, m1;
    m0 = ((const f32x4*)(mixk + ch))[0];
    m1 = ((const f32x4*)(mixk + ch))[1];
    *(ushort8*)(kx + off) = pack8(xc0 * m0 + xp0 * (one4 - m0),
                                  xc1 * m1 + xp1 * (one4 - m1));
    m0 = ((const f32x4*)(mixv + ch))[0];
    m1 = ((const f32x4*)(mixv + ch))[1];
    *(ushort8*)(vx + off) = pack8(xc0 * m0 + xp0 * (one4 - m0),
                                  xc1 * m1 + xp1 * (one4 - m1));
    m0 = ((const f32x4*)(mixr + ch))[0];
    m1 = ((const f32x4*)(mixr + ch))[1];
    *(ushort8*)(rx + off) = pack8(xc0 * m0 + xp0 * (one4 - m0),
                                  xc1 * m1 + xp1 * (one4 - m1));
}

// ---------------------------------------------------------------------------
// Kernel 3: out-of-place bf16 GEMM, m97 structure. C[m][n] = A[m][:] @ B[n][:],
// optional sigmoid epilogue. 128x128 tile, BK=32, 4 waves x (4x4) mfma.
// grid = (pn=4, pm=256): pn fastest so the 4 consumers of an A-tile
// co-schedule and share it in L2.
// ---------------------------------------------------------------------------
__global__ __launch_bounds__(256, 2) void gemm_one(
    const unsigned short* __restrict__ A,     // [MM][CC] bf16
    const unsigned short* __restrict__ Bw,    // [CC][CC] bf16, N-major
    unsigned short* __restrict__ Cb,          // [MM][CC] bf16 out
    int sig) {
    __shared__ unsigned short As[128 * 32];
    __shared__ unsigned short Bs[128 * 32];

    const int tid = threadIdx.x;
    const int pn = blockIdx.x, pm = blockIdx.y;

    const int r0 = tid >> 2;              // 0..63
    const int cc = (tid & 3) * 8;
    const unsigned short* ag0 = A + (size_t)(pm * 128 + r0) * CC + cc;
    const unsigned short* ag1 = ag0 + (size_t)64 * CC;
    const unsigned short* bg0 = Bw + (size_t)(pn * 128 + r0) * CC + cc;
    const unsigned short* bg1 = bg0 + (size_t)64 * CC;
    unsigned short* al0 = &As[tid * 8];
    unsigned short* al1 = &As[2048 + tid * 8];
    unsigned short* bl0 = &Bs[tid * 8];
    unsigned short* bl1 = &Bs[2048 + tid * 8];

    const int wave = tid >> 6, lane = tid & 63;
    const int wr_ = wave >> 1, wc_ = wave & 1;
    const int q = lane >> 4, l16 = lane & 15;

    f32x4 acc[4][4];
#pragma unroll
    for (int i = 0; i < 4; i++)
#pragma unroll
        for (int j = 0; j < 4; j++) acc[i][j] = (f32x4){0.f, 0.f, 0.f, 0.f};

    for (int kt = 0; kt < 16; ++kt) {
        const int k0 = kt * 32;
        gl_lds16(ag0 + k0, al0);
        gl_lds16(ag1 + k0, al1);
        gl_lds16(bg0 + k0, bl0);
        gl_lds16(bg1 + k0, bl1);

        __syncthreads();

        short8 a[4], b[4];
#pragma unroll
        for (int i = 0; i < 4; i++)
            a[i] = *(const short8*)&As[(wr_ * 64 + i * 16 + l16) * 32 + q * 8];
#pragma unroll
        for (int j = 0; j < 4; j++)
            b[j] = *(const short8*)&Bs[(wc_ * 64 + j * 16 + l16) * 32 + q * 8];
#pragma unroll
        for (int i = 0; i < 4; i++)
#pragma unroll
            for (int j = 0; j < 4; j++)
                acc[i][j] = __builtin_amdgcn_mfma_f32_16x16x32_bf16(a[i], b[j], acc[i][j], 0, 0, 0);

        __syncthreads();
    }

    const int gm0 = pm * 128 + wr_ * 64;
    const int gn0 = pn * 128 + wc_ * 64;
#pragma unroll
    for (int i = 0; i < 4; i++)
#pragma unroll
        for (int j = 0; j < 4; j++)
#pragma unroll
            for (int ii = 0; ii < 4; ii++) {
                const int m = gm0 + i * 16 + q * 4 + ii;
                const int n = gn0 + j * 16 + l16;
                float val = acc[i][j][ii];
                if (sig) val = 1.0f / (1.0f + __expf(-val));
                Cb[(size_t)m * CC + n] = f2bf(val);
            }
}

// ---------------------------------------------------------------------------
// WKV chunked parallel scan.
// ---------------------------------------------------------------------------
__global__ __launch_bounds__(256) void wkv_part1(
    const unsigned short* __restrict__ kb, const unsigned short* __restrict__ vb,
    const float* __restrict__ sd,
    float* __restrict__ sp_, float* __restrict__ sq_, float* __restrict__ so_) {
    const int idx = blockIdx.x * 256 + threadIdx.x;
    const int c = idx & (CC - 1);
    const int b = (idx >> 9) & (BB - 1);
    const int s = idx >> 12;
    const float w = sd[c] * (1.0f / (float)TT);
    const size_t base = ((size_t)b * TT + (size_t)s * LL) * CC + c;
    const unsigned short* kp = kb + base;
    const unsigned short* vp = vb + base;

    float p = 0.f, q = 0.f, o = -1e38f;
#pragma unroll 8
    for (int i = 0; i < LL; ++i) {
        const float kt = bf2f(kp[(size_t)i * CC]);
        const float vt = bf2f(vp[(size_t)i * CC]);
        const float no2 = fmaxf(w + o, kt);
        const float A2  = __expf(w + o - no2);
        const float B2  = __expf(kt - no2);
        p = A2 * p + B2 * vt;
        q = A2 * q + B2;
        o = no2;
    }
    sp_[idx] = p; sq_[idx] = q; so_[idx] = o;
}

__global__ __launch_bounds__(256) void wkv_part2(
    const float* __restrict__ sd,
    float* __restrict__ sp_, float* __restrict__ sq_, float* __restrict__ so_) {
    const int idx = blockIdx.x * 256 + threadIdx.x;
    const int c = idx & (CC - 1);
    const float wL = sd[c] * ((float)LL / (float)TT);

    float p = 0.f, q = 0.f, o = -1e38f;
    float lp = sp_[idx], lq = sq_[idx], lo = so_[idx];
    for (int s = 0; s < SS; ++s) {
        const int off = s * (BB * CC) + idx;
        float nlp = 0.f, nlq = 0.f, nlo = 0.f;
        if (s + 1 < SS) {
            nlp = sp_[off + BB * CC];
            nlq = sq_[off + BB * CC];
            nlo = so_[off + BB * CC];
        }
        sp_[off] = p; sq_[off] = q; so_[off] = o;
        const float no = fmaxf(o + wL, lo);
        const float A  = __expf(o + wL - no);
        const float Bc = __expf(lo - no);
        p = A * p + Bc * lp;
        q = A * q + Bc * lq;
        o = no;
        lp = nlp; lq = nlq; lo = nlo;
    }
}

// Pass 3: replay chunk from exclusive prefix; z = sr*y overwrites srb in place
// (element read by exactly the thread that writes it).
__global__ __launch_bounds__(256) void wkv_part3(
    const unsigned short* __restrict__ kb, const unsigned short* __restrict__ vb,
    unsigned short* __restrict__ srz,
    const float* __restrict__ sd, const float* __restrict__ sf,
    const float* __restrict__ sp_, const float* __restrict__ sq_,
    const float* __restrict__ so_) {
    const int idx = blockIdx.x * 256 + threadIdx.x;
    const int c = idx & (CC - 1);
    const int b = (idx >> 9) & (BB - 1);
    const int s = idx >> 12;
    const float w = sd[c] * (1.0f / (float)TT);
    const float u = sf[c] * (1.0f / (float)TT);
    const size_t base = ((size_t)b * TT + (size_t)s * LL) * CC + c;
    const unsigned short* kp = kb + base;
    const unsigned short* vp = vb + base;
    unsigned short* sp = srz + base;

    float p = sp_[idx], q = sq_[idx], o = so_[idx];
#pragma unroll 4
    for (int i = 0; i < LL; ++i) {
        const float kt = bf2f(kp[(size_t)i * CC]);
        const float vt = bf2f(vp[(size_t)i * CC]);
        const float sr = bf2f(sp[(size_t)i * CC]);

        const float no = fmaxf(o, u + kt);
        const float A  = __expf(o - no);
        const float Bt = __expf(u + kt - no);
        const float y  = (A * p + Bt * vt) / (A * q + Bt);
        sp[(size_t)i * CC] = f2bf(sr * y);

        const float no2 = fmaxf(w + o, kt);
        const float A2  = __expf(w + o - no2);
        const float B2  = __expf(kt - no2);
        p = A2 * p + B2 * vt;
        q = A2 * q + B2;
        o = no2;
    }
}

// ---------------------------------------------------------------------------
// Kernel 4: out = z @ wo (fp32 out)
// ---------------------------------------------------------------------------
__global__ __launch_bounds__(256, 2) void gemm_out(
    const unsigned short* __restrict__ zb, const unsigned short* __restrict__ woT,
    float* __restrict__ out) {
    __shared__ unsigned short As[128 * 32];
    __shared__ unsigned short Bs[128 * 32];

    const int tid = threadIdx.x;
    const int pn = blockIdx.x, pm = blockIdx.y;

    const int r0 = tid >> 2;
    const int cc = (tid & 3) * 8;
    const unsigned short* ag0 = zb + (size_t)(pm * 128 + r0) * CC + cc;
    const unsigned short* ag1 = ag0 + (size_t)64 * CC;
    const unsigned short* bg0 = woT + (size_t)(pn * 128 + r0) * CC + cc;
    const unsigned short* bg1 = bg0 + (size_t)64 * CC;
    unsigned short* al0 = &As[tid * 8];
    unsigned short* al1 = &As[2048 + tid * 8];
    unsigned short* bl0 = &Bs[tid * 8];
    unsigned short* bl1 = &Bs[2048 + tid * 8];

    const int wave = tid >> 6, lane = tid & 63;
    const int wr_ = wave >> 1, wc_ = wave & 1;
    const int q = lane >> 4, l16 = lane & 15;

    f32x4 acc[4][4];
#pragma unroll
    for (int i = 0; i < 4; i++)
#pragma unroll
        for (int j = 0; j < 4; j++) acc[i][j] = (f32x4){0.f, 0.f, 0.f, 0.f};

    for (int kt = 0; kt < 16; ++kt) {
        const int k0 = kt * 32;
        gl_lds16(ag0 + k0, al0);
        gl_lds16(ag1 + k0, al1);
        gl_lds16(bg0 + k0, bl0);
        gl_lds16(bg1 + k0, bl1);

        __syncthreads();

        short8 a[4], b[4];
#pragma unroll
        for (int i = 0; i < 4; i++)
            a[i] = *(const short8*)&As[(wr_ * 64 + i * 16 + l16) * 32 + q * 8];
#pragma unroll
        for (int j = 0; j < 4; j++)
            b[j] = *(const short8*)&Bs[(wc_ * 64 + j * 16 + l16) * 32 + q * 8];
#pragma unroll
        for (int i = 0; i < 4; i++)
#pragma unroll
            for (int j = 0; j < 4; j++)
                acc[i][j] = __builtin_amdgcn_mfma_f32_16x16x32_bf16(a[i], b[j], acc[i][j], 0, 0, 0);

        __syncthreads();
    }

    const int gm0 = pm * 128 + wr_ * 64;
    const int gn0 = pn * 128 + wc_ * 64;
#pragma unroll
    for (int i = 0; i < 4; i++)
#pragma unroll
        for (int j = 0; j < 4; j++)
#pragma unroll
            for (int ii = 0; ii < 4; ii++) {
                const int m = gm0 + i * 16 + q * 4 + ii;
                const int n = gn0 + j * 16 + l16;
                out[(size_t)m * CC + n] = acc[i][j][ii];
            }
}

// ---------------------------------------------------------------------------
extern "C" void kernel_launch(void* const* d_in, const int* in_sizes, int n_in,
                              void* d_out, int out_size, void* d_ws, size_t ws_size,
                              hipStream_t stream) {
    const float* x  = (const float*)d_in[0];
    const float* sd = (const float*)d_in[1];
    const float* sf = (const float*)d_in[2];
    const float* mk = (const float*)d_in[3];
    const float* mv = (const float*)d_in[4];
    const float* mr = (const float*)d_in[5];
    const float* wk = (const float*)d_in[6];
    const float* wv = (const float*)d_in[7];
    const float* wr = (const float*)d_in[8];
    const float* wo = (const float*)d_in[9];
    float* out = (float*)d_out;

    // ws layout (136 MiB total; proven-safe ceiling 194 MiB):
    //   wT   bf16 [4][512][512]   2 MiB
    //   buf0 bf16 [M][C] 32 MiB : mixed xk, then v (after v-GEMM)
    //   buf1 bf16 [M][C] 32 MiB : mixed xv
    //   buf2 bf16 [M][C] 32 MiB : mixed xr, then k (after k-GEMM)
    //   buf3 bf16 [M][C] 32 MiB : sr (after r-GEMM), then z (part3 in-place)
    //   sp/sq/so fp32 [S][B][C]  3 x 2 MiB
    // Rotation: r-GEMM buf2->buf3; k-GEMM buf0->buf2; v-GEMM buf1->buf0.
    char* ws = (char*)d_ws;
    unsigned short* wT = (unsigned short*)ws;
    unsigned short* buf0 = (unsigned short*)(ws + (size_t)4 * CC * CC * 2);
    unsigned short* buf1 = buf0 + (size_t)MM * CC;
    unsigned short* buf2 = buf1 + (size_t)MM * CC;
    unsigned short* buf3 = buf2 + (size_t)MM * CC;
    float* sp_ = (float*)(buf3 + (size_t)MM * CC);
    float* sq_ = sp_ + (size_t)SS * BB * CC;
    float* so_ = sq_ + (size_t)SS * BB * CC;
    unsigned short* wkT = wT;
    unsigned short* wvT = wT + (size_t)1 * CC * CC;
    unsigned short* wrT = wT + (size_t)2 * CC * CC;
    unsigned short* woT = wT + (size_t)3 * CC * CC;

    transpose_w<<<dim3((CC * CC) / 256, 4), 256, 0, stream>>>(wk, wv, wr, wo, wT);

    mix_kvr<<<dim3((MM * CC / 8) / 256), 256, 0, stream>>>(
        x, mk, mv, mr, buf0, buf1, buf2);

    // r first (frees buf2), then k (frees buf0), then v.
    gemm_one<<<dim3(4, MM / 128), 256, 0, stream>>>(buf2, wrT, buf3, 1); // sr
    gemm_one<<<dim3(4, MM / 128), 256, 0, stream>>>(buf0, wkT, buf2, 0); // k
    gemm_one<<<dim3(4, MM / 128), 256, 0, stream>>>(buf1, wvT, buf0, 0); // v

    // k in buf2, v in buf0, sr in buf3
    wkv_part1<<<dim3((SS * BB * CC) / 256), 256, 0, stream>>>(buf2, buf0, sd, sp_, sq_, so_);
    wkv_part2<<<dim3((BB * CC) / 256), 256, 0, stream>>>(sd, sp_, sq_, so_);
    wkv_part3<<<dim3((SS * BB * CC) / 256), 256, 0, stream>>>(
        buf2, buf0, buf3, sd, sf, sp_, sq_, so_);

    gemm_out<<<dim3(4, MM / 128), 256, 0, stream>>>(buf3, woT, out);
}